// Round 18
// baseline (102.292 us; speedup 1.0000x reference)
//
#include <hip/hip_runtime.h>
#include <hip/hip_bf16.h>

#define BATCH 4
#define CCH   256
#define SS    2304          // 48*48
#define NHEAD 8
#define HD    32
// fold 1/sqrt(32) * log2(e) into Q so softmax is raw exp2
#define SCALE_L2E (1.4426950408889634f * 0.17677669529663687f)

using bf16x8 = __attribute__((ext_vector_type(8))) short;
using v4s    = __attribute__((ext_vector_type(4))) short;
using v8s    = __attribute__((ext_vector_type(8))) short;
using f32x4  = __attribute__((ext_vector_type(4))) float;

static __device__ __forceinline__ unsigned short f2bf(float f) {
    union { float f; unsigned u; } a; a.f = f;
    unsigned r = a.u + 0x7fff + ((a.u >> 16) & 1);   // RNE
    return (unsigned short)(r >> 16);
}
static __device__ __forceinline__ unsigned pk2(float a, float b) {
    return (unsigned)f2bf(a) | ((unsigned)f2bf(b) << 16);
}
// native packed f32->bf16 (compiler emits v_cvt_pk_bf16_f32)
static __device__ __forceinline__ v4s pack4(float a, float b, float c, float d) {
    float2 lo; lo.x = a; lo.y = b;
    float2 hi; hi.x = c; hi.y = d;
    union { __hip_bfloat162 h2[2]; v4s s; } u;
    u.h2[0] = __float22bfloat162_rn(lo);
    u.h2[1] = __float22bfloat162_rn(hi);
    return u.s;
}

// ---------------- fused prep: W fp32->bf16 (blocks 0..1023) + x transpose (blocks 1024..1599) ----
__global__ __launch_bounds__(256) void prep(const float* __restrict__ Wq, const float* __restrict__ Wk,
                                            const float* __restrict__ Wv, const float* __restrict__ Wo,
                                            const float* __restrict__ x,
                                            unsigned short* __restrict__ wqkv, unsigned short* __restrict__ wo,
                                            unsigned short* __restrict__ xt) {
    __shared__ float T[64][65];
    const int tid = threadIdx.x;
    if (blockIdx.x < 1024) {
        const int idx = blockIdx.x * 256 + tid;
        if (idx < 768 * 256) {
            const int o = idx >> 8, c = idx & 255;
            const float v = (o < 256) ? Wq[idx] : (o < 512) ? Wk[(o - 256) * 256 + c] : Wv[(o - 512) * 256 + c];
            wqkv[idx] = f2bf(v);
        } else {
            const int j = idx - 768 * 256;
            wo[j] = f2bf(Wo[j]);
        }
    } else {
        const int e = blockIdx.x - 1024;         // 576 transpose tiles
        const int b = e / 144, rem = e % 144;
        const int c0 = (rem / 36) * 64, s0 = (rem % 36) * 64;
        #pragma unroll
        for (int p = 0; p < 16; ++p) {
            const int c = p * 4 + (tid >> 6), s = tid & 63;
            T[c][s] = x[((size_t)(b * CCH + c0 + c)) * SS + s0 + s];
        }
        __syncthreads();
        #pragma unroll
        for (int p = 0; p < 8; ++p) {
            const int s = p * 8 + (tid >> 5), c = (tid & 31) * 2;
            *(unsigned*)&xt[((size_t)(b * SS + s0 + s)) * CCH + c0 + c] = pk2(T[c][s], T[c + 1][s]);
        }
    }
}

// ---------------- fused QKV GEMM (bf16 MFMA, barrier-free), 2-wave blocks ----------------
// Q/K -> [bh][s][d] bf16 (Q pre-scaled by SCALE_L2E). V -> [b][c][s] bf16 plane.
__global__ __launch_bounds__(128) void gemm_qkv(const unsigned short* __restrict__ xt,
                                                const unsigned short* __restrict__ wqkv,
                                                const float* __restrict__ bq, const float* __restrict__ bk,
                                                const float* __restrict__ bv,
                                                unsigned short* __restrict__ qt, unsigned short* __restrict__ kt,
                                                unsigned short* __restrict__ vp) {
    __shared__ char Eb[2][9216];           // per-wave epilogue staging
    const int b  = blockIdx.z;
    const int o0 = blockIdx.x * 64, s0 = blockIdx.y * 64;
    const int tid = threadIdx.x, wid = tid >> 6, lane = tid & 63;
    const int lr = lane & 15, lg = lane >> 4;
    const int o_w = o0 + wid * 32, s_w = s0;

    const f32x4 zero4 = {0.f, 0.f, 0.f, 0.f};
    f32x4 acc[2][4];
    #pragma unroll
    for (int ai = 0; ai < 2; ++ai)
        #pragma unroll
        for (int bj = 0; bj < 4; ++bj) acc[ai][bj] = zero4;

    #pragma unroll
    for (int c0 = 0; c0 < 256; c0 += 32) {
        bf16x8 a[2], bb[4];
        #pragma unroll
        for (int ai = 0; ai < 2; ++ai)
            a[ai] = *(const bf16x8*)&wqkv[(size_t)(o_w + ai * 16 + lr) * 256 + c0 + lg * 8];
        #pragma unroll
        for (int bj = 0; bj < 4; ++bj)
            bb[bj] = *(const bf16x8*)&xt[((size_t)b * SS + s_w + bj * 16 + lr) * 256 + c0 + lg * 8];
        #pragma unroll
        for (int ai = 0; ai < 2; ++ai)
            #pragma unroll
            for (int bj = 0; bj < 4; ++bj)
                acc[ai][bj] = __builtin_amdgcn_mfma_f32_16x16x32_bf16(a[ai], bb[bj], acc[ai][bj], 0, 0, 0);
    }

    const int t = o0 >> 8;                 // 0=Q 1=K 2=V
    const int o_loc = o_w - t * 256;
    const float* bias = (t == 0) ? bq : (t == 1) ? bk : bv;

    float vals[2][4][4];
    #pragma unroll
    for (int ai = 0; ai < 2; ++ai)
        #pragma unroll
        for (int bj = 0; bj < 4; ++bj)
            #pragma unroll
            for (int i = 0; i < 4; ++i) {
                float vv = acc[ai][bj][i] + bias[o_loc + ai * 16 + 4 * lg + i];
                if (t == 0) vv *= SCALE_L2E;
                vals[ai][bj][i] = vv;
            }

    if (t < 2) {
        unsigned short* dst = (t == 0) ? qt : kt;
        unsigned short* Ls = (unsigned short*)Eb[wid];   // [64 s][40 o] bf16
        #pragma unroll
        for (int ai = 0; ai < 2; ++ai)
            #pragma unroll
            for (int bj = 0; bj < 4; ++bj) {
                uint2 w;
                w.x = pk2(vals[ai][bj][0], vals[ai][bj][1]);
                w.y = pk2(vals[ai][bj][2], vals[ai][bj][3]);
                *(uint2*)&Ls[(bj * 16 + lr) * 40 + ai * 16 + 4 * lg] = w;
            }
        const int h = o_loc >> 5;
        const size_t base = (size_t)(b * NHEAD + h) * SS;
        #pragma unroll
        for (int p = 0; p < 4; ++p) {
            const int cid = p * 64 + lane;
            const int s_loc = cid >> 2, oc = cid & 3;
            uint4 v = *(const uint4*)&Ls[s_loc * 40 + oc * 8];
            *(uint4*)&dst[(base + s_w + s_loc) * HD + oc * 8] = v;
        }
    } else {
        float* Lf = (float*)Eb[wid];                      // [32 o][68 s] f32
        #pragma unroll
        for (int ai = 0; ai < 2; ++ai)
            #pragma unroll
            for (int bj = 0; bj < 4; ++bj)
                #pragma unroll
                for (int i = 0; i < 4; ++i)
                    Lf[(ai * 16 + 4 * lg + i) * 68 + bj * 16 + lr] = vals[ai][bj][i];
        #pragma unroll
        for (int p = 0; p < 4; ++p) {
            const int cid = p * 64 + lane;
            const int oc = cid >> 3, sc8 = (cid & 7) * 8;
            float4 f0 = *(const float4*)&Lf[oc * 68 + sc8];
            float4 f1 = *(const float4*)&Lf[oc * 68 + sc8 + 4];
            uint4 w;
            w.x = pk2(f0.x, f0.y); w.y = pk2(f0.z, f0.w);
            w.z = pk2(f1.x, f1.y); w.w = pk2(f1.z, f1.w);
            *(uint4*)&vp[((size_t)(b * CCH) + o_loc + oc) * SS + s_w + sc8] = w;
        }
    }
}

// ---------------- MFMA flash attention v18: champion r10 + 4-way PV accumulator chains ------
// qt,kt: bf16 [bh][s][d]; vp: bf16 [b][c][s]; ot: bf16 [b][s][c]
// Block = 4 waves x 16 q-rows = 64 q/block; grid 1152. K/V staged once per block per 64-t
// tile into LDS fragment order ([tt][lane][16B], zero conflicts), double-buffered.
// PV accumulation split even/odd tt (accA/accB) -> 4 independent dependent-MFMA chains
// (was 2); psum add-chain split likewise. Everything else identical to the r15 champion.

#define SBAR __builtin_amdgcn_sched_barrier(0)

#define STAGE_LOAD(T0) do {                                                                \
    kreg = *(const v8s*)(ksrc + (size_t)(T0) * HD);                                        \
    vl   = *(const v4s*)(vsrc0 + (T0));                                                    \
    vh   = *(const v4s*)(vsrc1 + (T0));                                                    \
} while (0)

#define STAGE_WRITE(BUF) do {                                                              \
    *(v8s*)&Kbuf[BUF][wid * 512 + lane * 8] = kreg;                                        \
    *(v8s*)&Vbuf[BUF][wid * 512 + lane * 8] =                                              \
        __builtin_shufflevector(vl, vh, 0, 1, 2, 3, 4, 5, 6, 7);                           \
} while (0)

#define ATT_COMPUTE(BUF) do {                                                              \
    bf16x8 KF[4]; v8s VV[4];                                                               \
    _Pragma("unroll") for (int tt = 0; tt < 4; ++tt)                                       \
        KF[tt] = *(const bf16x8*)&Kbuf[BUF][tt * 512 + lane * 8];                          \
    _Pragma("unroll") for (int tt = 0; tt < 4; ++tt)                                       \
        VV[tt] = *(const v8s*)&Vbuf[BUF][tt * 512 + lane * 8];                             \
    f32x4 sc[4];                                                                           \
    _Pragma("unroll") for (int tt = 0; tt < 4; ++tt)                                       \
        sc[tt] = __builtin_amdgcn_mfma_f32_16x16x32_bf16(KF[tt], qf, zero4, 0, 0, 0);      \
    float p[16];                                                                           \
    _Pragma("unroll") for (int tt = 0; tt < 4; ++tt)                                       \
        _Pragma("unroll") for (int i = 0; i < 4; ++i)                                      \
            p[tt * 4 + i] = __builtin_amdgcn_exp2f(sc[tt][i]);                             \
    psumA += (p[0] + p[1]) + (p[2] + p[3]);                                                \
    psumB += (p[4] + p[5]) + (p[6] + p[7]);                                                \
    psumA += (p[8] + p[9]) + (p[10] + p[11]);                                              \
    psumB += (p[12] + p[13]) + (p[14] + p[15]);                                            \
    _Pragma("unroll") for (int tt = 0; tt < 4; ++tt) {                                     \
        const v4s pf = pack4(p[tt * 4], p[tt * 4 + 1], p[tt * 4 + 2], p[tt * 4 + 3]);      \
        const v4s v0 = __builtin_shufflevector(VV[tt], VV[tt], 0, 1, 2, 3);                \
        const v4s v1 = __builtin_shufflevector(VV[tt], VV[tt], 4, 5, 6, 7);                \
        if ((tt & 1) == 0) {                                                               \
            accA[0] = __builtin_amdgcn_mfma_f32_16x16x16bf16_1k(v0, pf, accA[0], 0, 0, 0); \
            accA[1] = __builtin_amdgcn_mfma_f32_16x16x16bf16_1k(v1, pf, accA[1], 0, 0, 0); \
        } else {                                                                           \
            accB[0] = __builtin_amdgcn_mfma_f32_16x16x16bf16_1k(v0, pf, accB[0], 0, 0, 0); \
            accB[1] = __builtin_amdgcn_mfma_f32_16x16x16bf16_1k(v1, pf, accB[1], 0, 0, 0); \
        }                                                                                  \
    }                                                                                      \
} while (0)

__global__ __launch_bounds__(256, 4) void attn(const unsigned short* __restrict__ qt,
                                               const unsigned short* __restrict__ kt,
                                               const unsigned short* __restrict__ vp,
                                               unsigned short* __restrict__ ot) {
    __shared__ short Kbuf[2][2048];   // [buf][tt*512 + lane*8]  (4KB/buf, fragment order)
    __shared__ short Vbuf[2][2048];   // [buf][tt*512 + lane*8]  low4=dh0, high4=dh1

    const int tid = threadIdx.x;
    const int wid = tid >> 6, lane = tid & 63;
    const int lr = lane & 15, lg = lane >> 4;

    const int bid = blockIdx.x;             // 1152 = 8 * 144
    const int xs = bid & 7, w = bid >> 3;   // XCD swizzle: 4 bh per XCD slot
    const int bh = xs * 4 + w / 36;
    const int q0 = (w % 36) * 64 + wid * 16;
    const int b  = bh >> 3, h = bh & 7;

    const unsigned short* qtb = qt + (size_t)bh * SS * HD;
    const unsigned short* ktb = kt + (size_t)bh * SS * HD;
    const unsigned short* vb  = vp + (size_t)(b * CCH + h * HD) * SS;

    // staging sources: this wave stages tt = wid of each tile
    const unsigned short* ksrc  = ktb + (size_t)(wid * 16 + lr) * HD + lg * 8;
    const unsigned short* vsrc0 = vb + (size_t)lr * SS + wid * 16 + lg * 4;
    const unsigned short* vsrc1 = vb + (size_t)(16 + lr) * SS + wid * 16 + lg * 4;

    const f32x4 zero4 = {0.f, 0.f, 0.f, 0.f};

    // Q fragment (B operand): col=lr=q, k-slots lg*8+j = d
    bf16x8 qf = *(const bf16x8*)&qtb[(size_t)(q0 + lr) * HD + lg * 8];

    f32x4 accA[2], accB[2];
    accA[0] = zero4; accA[1] = zero4; accB[0] = zero4; accB[1] = zero4;
    float psumA = 0.f, psumB = 0.f;

    v8s kreg; v4s vl, vh;

    STAGE_LOAD(0);
    STAGE_WRITE(0);
    __syncthreads();

    #pragma unroll 1
    for (int ii = 0; ii < 18; ++ii) {
        // phase A: compute buf0, stage tile 2ii+1 -> buf1
        STAGE_LOAD((2 * ii + 1) * 64);
        SBAR;
        ATT_COMPUTE(0);
        SBAR;
        STAGE_WRITE(1);
        __syncthreads();
        // phase B: compute buf1, stage tile 2ii+2 -> buf0 (skip on last)
        if (ii < 17) {
            STAGE_LOAD((2 * ii + 2) * 64);
        }
        SBAR;
        ATT_COMPUTE(1);
        SBAR;
        if (ii < 17) {
            STAGE_WRITE(0);
        }
        __syncthreads();
    }

    // merge chains, then reduce psum across lg groups (lanes sharing lr hold same q-row)
    float psum = psumA + psumB;
    psum += __shfl_xor(psum, 16);
    psum += __shfl_xor(psum, 32);

    const float inv = 1.f / psum;
    #pragma unroll
    for (int dh = 0; dh < 2; ++dh) {
        const float o0v = (accA[dh][0] + accB[dh][0]) * inv;
        const float o1v = (accA[dh][1] + accB[dh][1]) * inv;
        const float o2v = (accA[dh][2] + accB[dh][2]) * inv;
        const float o3v = (accA[dh][3] + accB[dh][3]) * inv;
        const v4s sv = pack4(o0v, o1v, o2v, o3v);
        *(v4s*)&ot[((size_t)b * SS + q0 + lr) * CCH + h * HD + dh * 16 + 4 * lg] = sv;
    }
}

// ---------------- output GEMM: out = Wo @ ot^T + bo + x (fp32), 2-wave blocks ----------------
__global__ __launch_bounds__(128) void gemm_o(const unsigned short* __restrict__ ot,
                                              const unsigned short* __restrict__ wo,
                                              const float* __restrict__ bo, const float* __restrict__ x,
                                              float* __restrict__ out) {
    const int b  = blockIdx.z;
    const int o0 = blockIdx.x * 64, s0 = blockIdx.y * 64;
    const int tid = threadIdx.x, wid = tid >> 6, lane = tid & 63;
    const int lr = lane & 15, lg = lane >> 4;
    const int o_w = o0 + wid * 32, s_w = s0;

    const f32x4 zero4 = {0.f, 0.f, 0.f, 0.f};
    f32x4 acc[2][4];
    #pragma unroll
    for (int ai = 0; ai < 2; ++ai)
        #pragma unroll
        for (int bj = 0; bj < 4; ++bj) acc[ai][bj] = zero4;

    #pragma unroll
    for (int c0 = 0; c0 < 256; c0 += 32) {
        bf16x8 a[2], bb[4];
        #pragma unroll
        for (int ai = 0; ai < 2; ++ai)
            a[ai] = *(const bf16x8*)&wo[(size_t)(o_w + ai * 16 + lr) * 256 + c0 + lg * 8];
        #pragma unroll
        for (int bj = 0; bj < 4; ++bj)
            bb[bj] = *(const bf16x8*)&ot[((size_t)b * SS + s_w + bj * 16 + lr) * 256 + c0 + lg * 8];
        #pragma unroll
        for (int ai = 0; ai < 2; ++ai)
            #pragma unroll
            for (int bj = 0; bj < 4; ++bj)
                acc[ai][bj] = __builtin_amdgcn_mfma_f32_16x16x32_bf16(a[ai], bb[bj], acc[ai][bj], 0, 0, 0);
    }

    #pragma unroll
    for (int ai = 0; ai < 2; ++ai)
        #pragma unroll
        for (int bj = 0; bj < 4; ++bj)
            #pragma unroll
            for (int i = 0; i < 4; ++i) {
                const int o = o_w + ai * 16 + 4 * lg + i;
                const int s = s_w + bj * 16 + lr;
                const size_t idx = (size_t)(b * CCH + o) * SS + s;
                out[idx] = acc[ai][bj][i] + bo[o] + x[idx];
            }
}

extern "C" void kernel_launch(void* const* d_in, const int* in_sizes, int n_in,
                              void* d_out, int out_size, void* d_ws, size_t ws_size,
                              hipStream_t stream) {
    const float* x  = (const float*)d_in[0];
    const float* Wq = (const float*)d_in[1];
    const float* bq = (const float*)d_in[2];
    const float* Wk = (const float*)d_in[3];
    const float* bk = (const float*)d_in[4];
    const float* Wv = (const float*)d_in[5];
    const float* bv = (const float*)d_in[6];
    const float* Wo = (const float*)d_in[7];
    const float* bo = (const float*)d_in[8];
    float* out = (float*)d_out;

    const size_t plane = (size_t)BATCH * CCH * SS;      // 2,359,296 elems
    unsigned short* xt   = (unsigned short*)d_ws;       // [b][s][c]
    unsigned short* qtw  = xt  + plane;                 // [bh][s][d]
    unsigned short* ktw  = qtw + plane;                 // [bh][s][d]
    unsigned short* vpw  = ktw + plane;                 // [b][c][s]
    unsigned short* otw  = vpw + plane;                 // [b][s][c]
    unsigned short* wqkv = otw + plane;                 // [768][256]
    unsigned short* wob  = wqkv + 768 * 256;            // [256][256]

    prep<<<dim3(1600), dim3(256), 0, stream>>>(Wq, Wk, Wv, Wo, x, wqkv, wob, xt);
    gemm_qkv<<<dim3(12, 36, BATCH), dim3(128), 0, stream>>>(xt, wqkv, bq, bk, bv, qtw, ktw, vpw);
    attn<<<dim3(1152), dim3(256), 0, stream>>>(qtw, ktw, vpw, otw);
    gemm_o<<<dim3(4, 36, BATCH), dim3(128), 0, stream>>>(otw, wob, bo, x, out);
}

// Round 19
// 96.722 us; speedup vs baseline: 1.0576x; 1.0576x over previous
//
#include <hip/hip_runtime.h>
#include <hip/hip_bf16.h>

#define BATCH 4
#define CCH   256
#define SS    2304          // 48*48
#define NHEAD 8
#define HD    32
// fold 1/sqrt(32) * log2(e) into Q so softmax is raw exp2
#define SCALE_L2E (1.4426950408889634f * 0.17677669529663687f)

using bf16x8 = __attribute__((ext_vector_type(8))) short;
using v4s    = __attribute__((ext_vector_type(4))) short;
using v8s    = __attribute__((ext_vector_type(8))) short;
using f32x4  = __attribute__((ext_vector_type(4))) float;

static __device__ __forceinline__ unsigned short f2bf(float f) {
    union { float f; unsigned u; } a; a.f = f;
    unsigned r = a.u + 0x7fff + ((a.u >> 16) & 1);   // RNE
    return (unsigned short)(r >> 16);
}
static __device__ __forceinline__ unsigned pk2(float a, float b) {
    return (unsigned)f2bf(a) | ((unsigned)f2bf(b) << 16);
}
// native packed f32->bf16 (compiler emits v_cvt_pk_bf16_f32)
static __device__ __forceinline__ v4s pack4(float a, float b, float c, float d) {
    float2 lo; lo.x = a; lo.y = b;
    float2 hi; hi.x = c; hi.y = d;
    union { __hip_bfloat162 h2[2]; v4s s; } u;
    u.h2[0] = __float22bfloat162_rn(lo);
    u.h2[1] = __float22bfloat162_rn(hi);
    return u.s;
}

// ---------------- fused prep: W fp32->bf16 (blocks 0..1023) + x transpose (blocks 1024..1599) ----
__global__ __launch_bounds__(256) void prep(const float* __restrict__ Wq, const float* __restrict__ Wk,
                                            const float* __restrict__ Wv, const float* __restrict__ Wo,
                                            const float* __restrict__ x,
                                            unsigned short* __restrict__ wqkv, unsigned short* __restrict__ wo,
                                            unsigned short* __restrict__ xt) {
    __shared__ float T[64][65];
    const int tid = threadIdx.x;
    if (blockIdx.x < 1024) {
        const int idx = blockIdx.x * 256 + tid;
        if (idx < 768 * 256) {
            const int o = idx >> 8, c = idx & 255;
            const float v = (o < 256) ? Wq[idx] : (o < 512) ? Wk[(o - 256) * 256 + c] : Wv[(o - 512) * 256 + c];
            wqkv[idx] = f2bf(v);
        } else {
            const int j = idx - 768 * 256;
            wo[j] = f2bf(Wo[j]);
        }
    } else {
        const int e = blockIdx.x - 1024;         // 576 transpose tiles
        const int b = e / 144, rem = e % 144;
        const int c0 = (rem / 36) * 64, s0 = (rem % 36) * 64;
        #pragma unroll
        for (int p = 0; p < 16; ++p) {
            const int c = p * 4 + (tid >> 6), s = tid & 63;
            T[c][s] = x[((size_t)(b * CCH + c0 + c)) * SS + s0 + s];
        }
        __syncthreads();
        #pragma unroll
        for (int p = 0; p < 8; ++p) {
            const int s = p * 8 + (tid >> 5), c = (tid & 31) * 2;
            *(unsigned*)&xt[((size_t)(b * SS + s0 + s)) * CCH + c0 + c] = pk2(T[c][s], T[c + 1][s]);
        }
    }
}

// ---------------- fused QKV GEMM (bf16 MFMA, barrier-free), 2-wave blocks ----------------
// Q/K -> [bh][s][d] bf16 (Q pre-scaled by SCALE_L2E). V -> [b][c][s] bf16 plane.
// Block = 128 thr = 2 waves; wave tile 32(o) x 64(s); grid (12, 36, B) = 1728 blocks.
__global__ __launch_bounds__(128) void gemm_qkv(const unsigned short* __restrict__ xt,
                                                const unsigned short* __restrict__ wqkv,
                                                const float* __restrict__ bq, const float* __restrict__ bk,
                                                const float* __restrict__ bv,
                                                unsigned short* __restrict__ qt, unsigned short* __restrict__ kt,
                                                unsigned short* __restrict__ vp) {
    __shared__ char Eb[2][9216];           // per-wave epilogue staging
    const int b  = blockIdx.z;
    const int o0 = blockIdx.x * 64, s0 = blockIdx.y * 64;
    const int tid = threadIdx.x, wid = tid >> 6, lane = tid & 63;
    const int lr = lane & 15, lg = lane >> 4;
    const int o_w = o0 + wid * 32, s_w = s0;

    const f32x4 zero4 = {0.f, 0.f, 0.f, 0.f};
    f32x4 acc[2][4];
    #pragma unroll
    for (int ai = 0; ai < 2; ++ai)
        #pragma unroll
        for (int bj = 0; bj < 4; ++bj) acc[ai][bj] = zero4;

    #pragma unroll
    for (int c0 = 0; c0 < 256; c0 += 32) {
        bf16x8 a[2], bb[4];
        #pragma unroll
        for (int ai = 0; ai < 2; ++ai)
            a[ai] = *(const bf16x8*)&wqkv[(size_t)(o_w + ai * 16 + lr) * 256 + c0 + lg * 8];
        #pragma unroll
        for (int bj = 0; bj < 4; ++bj)
            bb[bj] = *(const bf16x8*)&xt[((size_t)b * SS + s_w + bj * 16 + lr) * 256 + c0 + lg * 8];
        #pragma unroll
        for (int ai = 0; ai < 2; ++ai)
            #pragma unroll
            for (int bj = 0; bj < 4; ++bj)
                acc[ai][bj] = __builtin_amdgcn_mfma_f32_16x16x32_bf16(a[ai], bb[bj], acc[ai][bj], 0, 0, 0);
    }

    const int t = o0 >> 8;                 // 0=Q 1=K 2=V
    const int o_loc = o_w - t * 256;
    const float* bias = (t == 0) ? bq : (t == 1) ? bk : bv;

    float vals[2][4][4];
    #pragma unroll
    for (int ai = 0; ai < 2; ++ai)
        #pragma unroll
        for (int bj = 0; bj < 4; ++bj)
            #pragma unroll
            for (int i = 0; i < 4; ++i) {
                float vv = acc[ai][bj][i] + bias[o_loc + ai * 16 + 4 * lg + i];
                if (t == 0) vv *= SCALE_L2E;
                vals[ai][bj][i] = vv;
            }

    if (t < 2) {
        unsigned short* dst = (t == 0) ? qt : kt;
        unsigned short* Ls = (unsigned short*)Eb[wid];   // [64 s][40 o] bf16
        #pragma unroll
        for (int ai = 0; ai < 2; ++ai)
            #pragma unroll
            for (int bj = 0; bj < 4; ++bj) {
                uint2 w;
                w.x = pk2(vals[ai][bj][0], vals[ai][bj][1]);
                w.y = pk2(vals[ai][bj][2], vals[ai][bj][3]);
                *(uint2*)&Ls[(bj * 16 + lr) * 40 + ai * 16 + 4 * lg] = w;
            }
        const int h = o_loc >> 5;
        const size_t base = (size_t)(b * NHEAD + h) * SS;
        #pragma unroll
        for (int p = 0; p < 4; ++p) {
            const int cid = p * 64 + lane;
            const int s_loc = cid >> 2, oc = cid & 3;
            uint4 v = *(const uint4*)&Ls[s_loc * 40 + oc * 8];
            *(uint4*)&dst[(base + s_w + s_loc) * HD + oc * 8] = v;
        }
    } else {
        float* Lf = (float*)Eb[wid];                      // [32 o][68 s] f32
        #pragma unroll
        for (int ai = 0; ai < 2; ++ai)
            #pragma unroll
            for (int bj = 0; bj < 4; ++bj)
                #pragma unroll
                for (int i = 0; i < 4; ++i)
                    Lf[(ai * 16 + 4 * lg + i) * 68 + bj * 16 + lr] = vals[ai][bj][i];
        #pragma unroll
        for (int p = 0; p < 4; ++p) {
            const int cid = p * 64 + lane;
            const int oc = cid >> 3, sc8 = (cid & 7) * 8;
            float4 f0 = *(const float4*)&Lf[oc * 68 + sc8];
            float4 f1 = *(const float4*)&Lf[oc * 68 + sc8 + 4];
            uint4 w;
            w.x = pk2(f0.x, f0.y); w.y = pk2(f0.z, f0.w);
            w.z = pk2(f1.x, f1.y); w.w = pk2(f1.z, f1.w);
            *(uint4*)&vp[((size_t)(b * CCH) + o_loc + oc) * SS + s_w + sc8] = w;
        }
    }
}

// ---------------- MFMA flash attention (champion r10): 4 waves x 16 q-rows, LDS K/V ---------
// qt,kt: bf16 [bh][s][d]; vp: bf16 [b][c][s]; ot: bf16 [b][s][c]
// Block = 4 waves x 16 q-rows = 64 q/block; grid 1152 (~4.5 blk/CU, ~18 waves/CU).
// K/V staged once per block per 64-t tile into LDS fragment order ([tt][lane][16B],
// zero conflicts), double-buffered, load-early/write-late.

#define SBAR __builtin_amdgcn_sched_barrier(0)

#define STAGE_LOAD(T0) do {                                                                \
    kreg = *(const v8s*)(ksrc + (size_t)(T0) * HD);                                        \
    vl   = *(const v4s*)(vsrc0 + (T0));                                                    \
    vh   = *(const v4s*)(vsrc1 + (T0));                                                    \
} while (0)

#define STAGE_WRITE(BUF) do {                                                              \
    *(v8s*)&Kbuf[BUF][wid * 512 + lane * 8] = kreg;                                        \
    *(v8s*)&Vbuf[BUF][wid * 512 + lane * 8] =                                              \
        __builtin_shufflevector(vl, vh, 0, 1, 2, 3, 4, 5, 6, 7);                           \
} while (0)

#define ATT_COMPUTE(BUF) do {                                                              \
    bf16x8 KF[4]; v8s VV[4];                                                               \
    _Pragma("unroll") for (int tt = 0; tt < 4; ++tt)                                       \
        KF[tt] = *(const bf16x8*)&Kbuf[BUF][tt * 512 + lane * 8];                          \
    _Pragma("unroll") for (int tt = 0; tt < 4; ++tt)                                       \
        VV[tt] = *(const v8s*)&Vbuf[BUF][tt * 512 + lane * 8];                             \
    f32x4 sc[4];                                                                           \
    _Pragma("unroll") for (int tt = 0; tt < 4; ++tt)                                       \
        sc[tt] = __builtin_amdgcn_mfma_f32_16x16x32_bf16(KF[tt], qf, zero4, 0, 0, 0);      \
    float p[16];                                                                           \
    _Pragma("unroll") for (int tt = 0; tt < 4; ++tt)                                       \
        _Pragma("unroll") for (int i = 0; i < 4; ++i)                                      \
            p[tt * 4 + i] = __builtin_amdgcn_exp2f(sc[tt][i]);                             \
    _Pragma("unroll") for (int tt = 0; tt < 4; ++tt)                                       \
        psum += (p[tt * 4] + p[tt * 4 + 1]) + (p[tt * 4 + 2] + p[tt * 4 + 3]);             \
    _Pragma("unroll") for (int tt = 0; tt < 4; ++tt) {                                     \
        const v4s pf = pack4(p[tt * 4], p[tt * 4 + 1], p[tt * 4 + 2], p[tt * 4 + 3]);      \
        const v4s v0 = __builtin_shufflevector(VV[tt], VV[tt], 0, 1, 2, 3);                \
        const v4s v1 = __builtin_shufflevector(VV[tt], VV[tt], 4, 5, 6, 7);                \
        acc[0] = __builtin_amdgcn_mfma_f32_16x16x16bf16_1k(v0, pf, acc[0], 0, 0, 0);       \
        acc[1] = __builtin_amdgcn_mfma_f32_16x16x16bf16_1k(v1, pf, acc[1], 0, 0, 0);       \
    }                                                                                      \
} while (0)

__global__ __launch_bounds__(256, 4) void attn(const unsigned short* __restrict__ qt,
                                               const unsigned short* __restrict__ kt,
                                               const unsigned short* __restrict__ vp,
                                               unsigned short* __restrict__ ot) {
    __shared__ short Kbuf[2][2048];   // [buf][tt*512 + lane*8]  (4KB/buf, fragment order)
    __shared__ short Vbuf[2][2048];   // [buf][tt*512 + lane*8]  low4=dh0, high4=dh1

    const int tid = threadIdx.x;
    const int wid = tid >> 6, lane = tid & 63;
    const int lr = lane & 15, lg = lane >> 4;

    const int bid = blockIdx.x;             // 1152 = 8 * 144
    const int xs = bid & 7, w = bid >> 3;   // XCD swizzle: 4 bh per XCD slot
    const int bh = xs * 4 + w / 36;
    const int q0 = (w % 36) * 64 + wid * 16;
    const int b  = bh >> 3, h = bh & 7;

    const unsigned short* qtb = qt + (size_t)bh * SS * HD;
    const unsigned short* ktb = kt + (size_t)bh * SS * HD;
    const unsigned short* vb  = vp + (size_t)(b * CCH + h * HD) * SS;

    // staging sources: this wave stages tt = wid of each tile
    const unsigned short* ksrc  = ktb + (size_t)(wid * 16 + lr) * HD + lg * 8;
    const unsigned short* vsrc0 = vb + (size_t)lr * SS + wid * 16 + lg * 4;
    const unsigned short* vsrc1 = vb + (size_t)(16 + lr) * SS + wid * 16 + lg * 4;

    const f32x4 zero4 = {0.f, 0.f, 0.f, 0.f};

    // Q fragment (B operand): col=lr=q, k-slots lg*8+j = d
    bf16x8 qf = *(const bf16x8*)&qtb[(size_t)(q0 + lr) * HD + lg * 8];

    f32x4 acc[2];
    acc[0] = zero4; acc[1] = zero4;
    float psum = 0.f;

    v8s kreg; v4s vl, vh;

    STAGE_LOAD(0);
    STAGE_WRITE(0);
    __syncthreads();

    #pragma unroll 1
    for (int ii = 0; ii < 18; ++ii) {
        // phase A: compute buf0, stage tile 2ii+1 -> buf1
        STAGE_LOAD((2 * ii + 1) * 64);
        SBAR;
        ATT_COMPUTE(0);
        SBAR;
        STAGE_WRITE(1);
        __syncthreads();
        // phase B: compute buf1, stage tile 2ii+2 -> buf0 (skip on last)
        if (ii < 17) {
            STAGE_LOAD((2 * ii + 2) * 64);
        }
        SBAR;
        ATT_COMPUTE(1);
        SBAR;
        if (ii < 17) {
            STAGE_WRITE(0);
        }
        __syncthreads();
    }

    // psum: lanes sharing lr hold the same q-row; reduce across lg groups
    psum += __shfl_xor(psum, 16);
    psum += __shfl_xor(psum, 32);

    const float inv = 1.f / psum;
    #pragma unroll
    for (int dh = 0; dh < 2; ++dh) {
        const float o0v = acc[dh][0] * inv;
        const float o1v = acc[dh][1] * inv;
        const float o2v = acc[dh][2] * inv;
        const float o3v = acc[dh][3] * inv;
        const v4s sv = pack4(o0v, o1v, o2v, o3v);
        *(v4s*)&ot[((size_t)b * SS + q0 + lr) * CCH + h * HD + dh * 16 + 4 * lg] = sv;
    }
}

// ---------------- output GEMM: out = Wo @ ot^T + bo + x (fp32), 2-wave blocks ----------------
__global__ __launch_bounds__(128) void gemm_o(const unsigned short* __restrict__ ot,
                                              const unsigned short* __restrict__ wo,
                                              const float* __restrict__ bo, const float* __restrict__ x,
                                              float* __restrict__ out) {
    const int b  = blockIdx.z;
    const int o0 = blockIdx.x * 64, s0 = blockIdx.y * 64;
    const int tid = threadIdx.x, wid = tid >> 6, lane = tid & 63;
    const int lr = lane & 15, lg = lane >> 4;
    const int o_w = o0 + wid * 32, s_w = s0;

    const f32x4 zero4 = {0.f, 0.f, 0.f, 0.f};
    f32x4 acc[2][4];
    #pragma unroll
    for (int ai = 0; ai < 2; ++ai)
        #pragma unroll
        for (int bj = 0; bj < 4; ++bj) acc[ai][bj] = zero4;

    #pragma unroll
    for (int c0 = 0; c0 < 256; c0 += 32) {
        bf16x8 a[2], bb[4];
        #pragma unroll
        for (int ai = 0; ai < 2; ++ai)
            a[ai] = *(const bf16x8*)&wo[(size_t)(o_w + ai * 16 + lr) * 256 + c0 + lg * 8];
        #pragma unroll
        for (int bj = 0; bj < 4; ++bj)
            bb[bj] = *(const bf16x8*)&ot[((size_t)b * SS + s_w + bj * 16 + lr) * 256 + c0 + lg * 8];
        #pragma unroll
        for (int ai = 0; ai < 2; ++ai)
            #pragma unroll
            for (int bj = 0; bj < 4; ++bj)
                acc[ai][bj] = __builtin_amdgcn_mfma_f32_16x16x32_bf16(a[ai], bb[bj], acc[ai][bj], 0, 0, 0);
    }

    #pragma unroll
    for (int ai = 0; ai < 2; ++ai)
        #pragma unroll
        for (int bj = 0; bj < 4; ++bj)
            #pragma unroll
            for (int i = 0; i < 4; ++i) {
                const int o = o_w + ai * 16 + 4 * lg + i;
                const int s = s_w + bj * 16 + lr;
                const size_t idx = (size_t)(b * CCH + o) * SS + s;
                out[idx] = acc[ai][bj][i] + bo[o] + x[idx];
            }
}

extern "C" void kernel_launch(void* const* d_in, const int* in_sizes, int n_in,
                              void* d_out, int out_size, void* d_ws, size_t ws_size,
                              hipStream_t stream) {
    const float* x  = (const float*)d_in[0];
    const float* Wq = (const float*)d_in[1];
    const float* bq = (const float*)d_in[2];
    const float* Wk = (const float*)d_in[3];
    const float* bk = (const float*)d_in[4];
    const float* Wv = (const float*)d_in[5];
    const float* bv = (const float*)d_in[6];
    const float* Wo = (const float*)d_in[7];
    const float* bo = (const float*)d_in[8];
    float* out = (float*)d_out;

    const size_t plane = (size_t)BATCH * CCH * SS;      // 2,359,296 elems
    unsigned short* xt   = (unsigned short*)d_ws;       // [b][s][c]
    unsigned short* qtw  = xt  + plane;                 // [bh][s][d]
    unsigned short* ktw  = qtw + plane;                 // [bh][s][d]
    unsigned short* vpw  = ktw + plane;                 // [b][c][s]
    unsigned short* otw  = vpw + plane;                 // [b][s][c]
    unsigned short* wqkv = otw + plane;                 // [768][256]
    unsigned short* wob  = wqkv + 768 * 256;            // [256][256]

    prep<<<dim3(1600), dim3(256), 0, stream>>>(Wq, Wk, Wv, Wo, x, wqkv, wob, xt);
    gemm_qkv<<<dim3(12, 36, BATCH), dim3(128), 0, stream>>>(xt, wqkv, bq, bk, bv, qtw, ktw, vpw);
    attn<<<dim3(1152), dim3(256), 0, stream>>>(qtw, ktw, vpw, otw);
    gemm_o<<<dim3(4, 36, BATCH), dim3(128), 0, stream>>>(otw, wob, bo, x, out);
}